// Round 18
// baseline (608.231 us; speedup 1.0000x reference)
//
#include <hip/hip_runtime.h>
#include <hip/hip_bf16.h>

#define D 128
#define NGRAPHS 64
#define PSPLIT 16

typedef short short8 __attribute__((ext_vector_type(8)));
typedef float f32x4 __attribute__((ext_vector_type(4)));
typedef float f32x16 __attribute__((ext_vector_type(16)));

__device__ __forceinline__ float sigf(float x) { return 1.0f / (1.0f + __expf(-x)); }

__device__ __forceinline__ unsigned short f2bf(float x) {
    unsigned u = __float_as_uint(x);
    return (unsigned short)((u + 0x7fffu + ((u >> 16) & 1u)) >> 16);
}
__device__ __forceinline__ float bf2f(unsigned short u) {
    return __uint_as_float(((unsigned)u) << 16);
}
__device__ __forceinline__ void splitf(float x, unsigned short& hb, unsigned short& lb) {
    hb = f2bf(x);
    lb = f2bf(x - bf2f(hb));
}
#define MFMA(a, b, c) __builtin_amdgcn_mfma_f32_16x16x32_bf16((a), (b), (c), 0, 0, 0)
#define MFMA32(a, b, c) __builtin_amdgcn_mfma_f32_32x32x16_bf16((a), (b), (c), 0, 0, 0)

// async global->LDS, 16B per lane; LDS dest wave-uniform base (+lane*16 implicit)
__device__ __forceinline__ void g2lds16(const unsigned short* g, unsigned short* l) {
    __builtin_amdgcn_global_load_lds(
        (const __attribute__((address_space(1))) void*)g,
        (__attribute__((address_space(3))) void*)l, 16, 0, 0);
}

// XCD-aware block swizzle: all GY col-groups of one row-tile share bid%8 (same XCD L2)
__device__ __forceinline__ void swzmap(int bid, int rowTiles, int GY, int& rt, int& cgp) {
    int chunk = GY << 3;
    int nfull = rowTiles >> 3;
    int fullB = nfull * chunk;
    if (bid < fullB) {
        int q = bid / chunk, r = bid - q * chunk;
        rt = (q << 3) + (r & 7);
        cgp = r >> 3;
    } else {
        int tail = rowTiles - (nfull << 3);
        int rem = bid - fullB;
        rt = (nfull << 3) + rem % tail;
        cgp = rem / tail;
    }
}

// ---------------- composite weights: Wm*=Whm@B, Ws*=Whs@B, c*=bci@B+b2 (B in {Whg,Whl}) ----------------
__global__ void compose_kernel(const float* __restrict__ Whm, const float* __restrict__ Whs,
                               const float* __restrict__ Whg, const float* __restrict__ Whl,
                               const float* __restrict__ bhm, const float* __restrict__ bhs,
                               const float* __restrict__ bias_h,
                               const float* __restrict__ bhg, const float* __restrict__ bhl,
                               float* __restrict__ Wmg, float* __restrict__ Wsg,
                               float* __restrict__ Wml, float* __restrict__ Wsl,
                               float* __restrict__ cg, float* __restrict__ cl) {
    const int sel = blockIdx.x;
    const int r = blockIdx.y;
    const float* B = sel ? Whl : Whg;
    if (r < 128) {
        const int half = threadIdx.x >> 7;
        const int c = threadIdx.x & 127;
        const float* A = half ? Whs : Whm;
        float* O = sel ? (half ? Wsl : Wml) : (half ? Wsg : Wmg);
        float acc = 0.f;
        for (int k = 0; k < 128; ++k) acc += A[r * 128 + k] * B[k * 128 + c];
        O[r * 128 + c] = acc;
    } else if (threadIdx.x < 128) {
        const int c = threadIdx.x;
        float acc = sel ? bhl[c] : bhg[c];
        for (int k = 0; k < 128; ++k)
            acc += (bhm[k] + bhs[k] + bias_h[k]) * B[k * 128 + c];
        (sel ? cl : cg)[c] = acc;
    }
}

// ---------------- weight prep (16x16 frag order) for the 2 single-mode matrices ----------------
// frag index f = ((j*4 + t)*64 + lane)*8 + s  maps to  W[t*32 + (lane>>4)*8 + s][j*16 + (lane&15)]
__global__ void wprepS_kernel(const float* w0, const float* w1, unsigned short* out) {
    const float* W = blockIdx.x ? w1 : w0;
    unsigned short* oh = out + (size_t)blockIdx.x * 32768;
    unsigned short* ol = oh + 16384;
    for (int f = threadIdx.x; f < 16384; f += 256) {
        int s = f & 7;
        int lane = (f >> 3) & 63;
        int t = (f >> 9) & 3;
        int j = f >> 11;
        int k = t * 32 + ((lane >> 4) << 3) + s;
        int c = (j << 4) + (lane & 15);
        unsigned short hb, lb;
        splitf(W[k * 128 + c], hb, lb);
        oh[f] = hb;
        ol[f] = lb;
    }
}

// ---------------- weight prep (32x32 frag order) for the 8 dual-mode matrices ----------------
// layout per matrix: [cg 0..3][plane hi/lo][ks 0..7][lane 0..63][s 0..7]
// element: W[ks*16 + (lane>>5)*8 + s][cg*32 + (lane&31)]
__global__ void wprepD_kernel(const float* w0, const float* w1, const float* w2, const float* w3,
                              const float* w4, const float* w5, const float* w6, const float* w7,
                              unsigned short* out) {
    const float* ws[8] = {w0, w1, w2, w3, w4, w5, w6, w7};
    const float* W = ws[blockIdx.x];
    unsigned short* ob = out + (size_t)blockIdx.x * 32768;
    for (int f = threadIdx.x; f < 16384; f += 256) {
        int s = f & 7;
        int lane = (f >> 3) & 63;
        int ks = (f >> 9) & 7;
        int cg = f >> 12;
        int k = ks * 16 + ((lane >> 5) << 3) + s;
        int col = cg * 32 + (lane & 31);
        unsigned short hb, lb;
        splitf(W[k * 128 + col], hb, lb);
        ob[cg * 8192 + ks * 512 + lane * 8 + s] = hb;
        ob[cg * 8192 + 4096 + ks * 512 + lane * 8 + s] = lb;
    }
}

// ---------------- DUAL 32x32 MFMA kernel (ZR / GH2), W in LDS, epilogue reuses W-LDS ----------------
// Block = 4 waves x 32 rows = 128 rows x 32 cols; grid = (rowTiles128 * 4) swizzled.
// MODE 1: ZR: z = sig(m@Wzm + h@Wzs + b0) -> C f32; rh = sig(m@Wrm + h@Wrs + b1)*h -> planes
// MODE 3: GH2: g = sig(m@Wmg + rh@Wsg + b0); ht = (m@Wml + rh@Wsl + b1)*g;
//         h = z*ht + (1-z)*h_old -> planes   [auxf = z]
template <int MODE>
__launch_bounds__(256)
__global__ void gmm32(const unsigned short* __restrict__ A0h, const unsigned short* __restrict__ A0l,
                      const unsigned short* __restrict__ A1h, const unsigned short* __restrict__ A1l,
                      const unsigned short* __restrict__ WA0, const unsigned short* __restrict__ WB0,
                      const unsigned short* __restrict__ WA1, const unsigned short* __restrict__ WB1,
                      float* __restrict__ C, unsigned short* __restrict__ Ph, unsigned short* __restrict__ Pl,
                      int N, int rowTiles,
                      const float* __restrict__ bias0, const float* __restrict__ bias1,
                      const float* __restrict__ auxf,
                      const unsigned short* __restrict__ auxh, const unsigned short* __restrict__ auxl) {
    __shared__ unsigned short ldsW[4 * 8192];   // 64KB; reused by epilogue transpose

    int rtile, by;
    swzmap(blockIdx.x, rowTiles, 4, rtile, by);

    const int tid = threadIdx.x;
    const int wave = tid >> 6;
    const int lane = tid & 63;
    const int r0w = rtile * 128 + wave * 32;

    // ---- stage 4 W slices (32 cols x K=128, hi+lo) into LDS: 64 x 1KB chunks ----
#pragma unroll
    for (int i = 0; i < 16; ++i) {
        int c = i * 4 + wave;
        int mat = c >> 4, rem = c & 15;
        int plane = rem >> 3, ks = rem & 7;
        const unsigned short* Wsrc = (mat == 0) ? WA0 : (mat == 1) ? WB0 : (mat == 2) ? WA1 : WB1;
        const unsigned short* gsrc = Wsrc + by * 8192 + plane * 4096 + ks * 512 + lane * 8;
        unsigned short* ldst = &ldsW[mat * 8192 + plane * 4096 + ks * 512];
        g2lds16(gsrc, ldst);
    }

    int r = r0w + (lane & 31);
    const int arow = (r < N) ? r : (N - 1);   // clamped rows never stored
    const int kofs = (lane >> 5) << 3;
    __syncthreads();

    f32x16 accA, accB;
#pragma unroll
    for (int i = 0; i < 16; ++i) { accA[i] = 0.f; accB[i] = 0.f; }

    // ---- main loop: 2 passes x 8 k-steps; pure A-load + ds_read + MFMA32 ----
#pragma unroll
    for (int p = 0; p < 2; ++p) {
        const unsigned short* __restrict__ Ah = p ? A1h : A0h;
        const unsigned short* __restrict__ Al = p ? A1l : A0l;
        const int matA = p * 2, matB = p * 2 + 1;
#pragma unroll
        for (int ks = 0; ks < 8; ++ks) {
            size_t ab = (size_t)arow * D + ks * 16 + kofs;
            short8 ah = *(const short8*)(Ah + ab);
            short8 al = *(const short8*)(Al + ab);
            const unsigned short* whp = &ldsW[matA * 8192 + ks * 512 + lane * 8];
            short8 wh = *(const short8*)whp;
            short8 wl = *(const short8*)(whp + 4096);
            accA = MFMA32(ah, wh, accA);
            accA = MFMA32(al, wh, accA);
            accA = MFMA32(ah, wl, accA);
            const unsigned short* vhp = &ldsW[matB * 8192 + ks * 512 + lane * 8];
            short8 vh = *(const short8*)vhp;
            short8 vl = *(const short8*)(vhp + 4096);
            accB = MFMA32(ah, vh, accB);
            accB = MFMA32(al, vh, accB);
            accB = MFMA32(ah, vl, accB);
        }
    }

    // ---- epilogue: reuse ldsW for the 32x32 C/D transpose (barrier: all waves done with W) ----
    __syncthreads();
    float* mw = (float*)ldsW + wave * 544;    // 16 rows x 34 stride per wave
    const int lr = lane >> 2;                 // read-back row 0..15
    const int cs = (lane & 3) * 8;            // 8 cols per lane
    const int col32 = lane & 31;
    const int rlo = (lane >> 5) << 2;         // +4 rows for hi lane half
    const int gcol = by * 32 + cs;

#pragma unroll
    for (int half = 0; half < 2; ++half) {
        // stage accA regs [half*8, half*8+8) -> rows 0..15 of this half
#pragma unroll
        for (int q = 0; q < 8; ++q) {
            int row = (q & 3) + 8 * (q >> 2) + rlo;
            mw[row * 34 + col32] = accA[half * 8 + q];
        }
        float vA[8];
#pragma unroll
        for (int k = 0; k < 8; k += 4)
            *(f32x4*)&vA[k] = *(const f32x4*)&mw[lr * 34 + cs + k];
        // stage accB (wave-lockstep reuse)
#pragma unroll
        for (int q = 0; q < 8; ++q) {
            int row = (q & 3) + 8 * (q >> 2) + rlo;
            mw[row * 34 + col32] = accB[half * 8 + q];
        }
        float vB[8];
#pragma unroll
        for (int k = 0; k < 8; k += 4)
            *(f32x4*)&vB[k] = *(const f32x4*)&mw[lr * 34 + cs + k];

        const int grow = r0w + half * 16 + lr;
        if (grow < N) {
            size_t ob = (size_t)grow * D + gcol;
            float4 b0a = *(const float4*)(bias0 + gcol);
            float4 b0b = *(const float4*)(bias0 + gcol + 4);
            float4 b1a = *(const float4*)(bias1 + gcol);
            float4 b1b = *(const float4*)(bias1 + gcol + 4);
            float b0v[8] = {b0a.x, b0a.y, b0a.z, b0a.w, b0b.x, b0b.y, b0b.z, b0b.w};
            float b1v[8] = {b1a.x, b1a.y, b1a.z, b1a.w, b1b.x, b1b.y, b1b.z, b1b.w};
            short8 hh8 = *(const short8*)(auxh + ob);
            short8 ll8 = *(const short8*)(auxl + ob);
            if (MODE == 1) {
                float zv[8];
                short8 sh, sl;
#pragma unroll
                for (int k = 0; k < 8; ++k) {
                    zv[k] = sigf(vA[k] + b0v[k]);
                    float rr = sigf(vB[k] + b1v[k]);
                    float hv = bf2f((unsigned short)hh8[k]) + bf2f((unsigned short)ll8[k]);
                    unsigned short hb, lb;
                    splitf(rr * hv, hb, lb);
                    sh[k] = (short)hb; sl[k] = (short)lb;
                }
                *(float4*)(C + ob) = make_float4(zv[0], zv[1], zv[2], zv[3]);
                *(float4*)(C + ob + 4) = make_float4(zv[4], zv[5], zv[6], zv[7]);
                *(short8*)(Ph + ob) = sh;
                *(short8*)(Pl + ob) = sl;
            } else {  // MODE 3
                float4 za = *(const float4*)(auxf + ob);
                float4 zb = *(const float4*)(auxf + ob + 4);
                float zzv[8] = {za.x, za.y, za.z, za.w, zb.x, zb.y, zb.z, zb.w};
                short8 sh, sl;
#pragma unroll
                for (int k = 0; k < 8; ++k) {
                    float g = sigf(vA[k] + b0v[k]);
                    float ht = (vB[k] + b1v[k]) * g;
                    float hv = bf2f((unsigned short)hh8[k]) + bf2f((unsigned short)ll8[k]);
                    float v = zzv[k] * ht + (1.f - zzv[k]) * hv;
                    unsigned short hb, lb;
                    splitf(v, hb, lb);
                    sh[k] = (short)hb; sl[k] = (short)lb;
                }
                *(short8*)(Ph + ob) = sh;
                *(short8*)(Pl + ob) = sl;
            }
        }
    }
}

// ---------------- SINGLE-mode 16x16 MFMA kernel (t = h@Wa, emb), W in LDS ----------------
// MODE 0: C = A0@W (f32, no bias)    MODE 4: relu(A0@W + b0) -> C f32
template <int MODE, int NJ, int RT>
__launch_bounds__(256)
__global__ void gmm(const unsigned short* __restrict__ A0h, const unsigned short* __restrict__ A0l,
                    const unsigned short* __restrict__ WA0,
                    float* __restrict__ C, int N, int rowTiles,
                    const float* __restrict__ bias0) {
    constexpr int COLS = NJ * 16;
    constexpr int STRIDE = COLS + 4;
    constexpr int CPL = COLS / 4;
    constexpr int GY = 8 / NJ;
    constexpr int MATSH = NJ * 4096;
    constexpr int CPM = NJ * 8;

    __shared__ unsigned short ldsW[MATSH];
    __shared__ float sm[4 * 16 * STRIDE];

    int rtile, by;
    swzmap(blockIdx.x, rowTiles, GY, rtile, by);

    const int tid = threadIdx.x;
    const int wave = tid >> 6;
    const int lane = tid & 63;
    const int r0 = rtile * (64 * RT) + wave * (16 * RT);

#pragma unroll
    for (int i = 0; i < CPM / 4; ++i) {
        int c = i * 4 + wave;
        int part = c / (NJ * 4);
        int sub = c - part * (NJ * 4);
        const unsigned short* gsrc = WA0 + part * 16384 + by * (NJ * 2048) + sub * 512 + lane * 8;
        unsigned short* ldst = &ldsW[part * (NJ * 2048) + sub * 512];
        g2lds16(gsrc, ldst);
    }
    __syncthreads();

    f32x4 accA[RT][NJ];
#pragma unroll
    for (int rt = 0; rt < RT; ++rt)
#pragma unroll
        for (int j = 0; j < NJ; ++j) accA[rt][j] = (f32x4){0.f, 0.f, 0.f, 0.f};

    int arow[RT];
#pragma unroll
    for (int rt = 0; rt < RT; ++rt) {
        int r = r0 + rt * 16 + (lane & 15);
        arow[rt] = (r < N) ? r : (N - 1);
    }
    const int kofs = (lane >> 4) << 3;

#pragma unroll
    for (int t = 0; t < 4; ++t) {
        short8 ah[RT], al[RT];
#pragma unroll
        for (int rt = 0; rt < RT; ++rt) {
            size_t ab = (size_t)arow[rt] * D + t * 32 + kofs;
            ah[rt] = *(const short8*)(A0h + ab);
            al[rt] = *(const short8*)(A0l + ab);
        }
#pragma unroll
        for (int jl = 0; jl < NJ; ++jl) {
            int fo = (((jl << 2) + t) << 6) * 8 + lane * 8;
            const unsigned short* whp = &ldsW[fo];
            short8 wh = *(const short8*)whp;
            short8 wl = *(const short8*)(whp + NJ * 2048);
#pragma unroll
            for (int rt = 0; rt < RT; ++rt) {
                accA[rt][jl] = MFMA(ah[rt], wh, accA[rt][jl]);
                accA[rt][jl] = MFMA(al[rt], wh, accA[rt][jl]);
                accA[rt][jl] = MFMA(ah[rt], wl, accA[rt][jl]);
            }
        }
    }

    float* mw = sm + wave * (16 * STRIDE);
    const int col0 = lane & 15;
    const int rb = (lane >> 4) << 2;
    const int lr = lane >> 2;
    const int cs = (lane & 3) * CPL;
    const int gcol = by * COLS + cs;

#pragma unroll
    for (int rt = 0; rt < RT; ++rt) {
        const int grow = r0 + rt * 16 + lr;
        const bool live = (grow < N);
        const size_t obase = (size_t)grow * D + gcol;

        float vA[CPL];
#pragma unroll
        for (int jl = 0; jl < NJ; ++jl)
#pragma unroll
            for (int reg = 0; reg < 4; ++reg)
                mw[(rb + reg) * STRIDE + jl * 16 + col0] = accA[rt][jl][reg];
#pragma unroll
        for (int k = 0; k < CPL; k += 4)
            *(f32x4*)&vA[k] = *(const f32x4*)&mw[lr * STRIDE + cs + k];

        if (live) {
#pragma unroll
            for (int s8 = 0; s8 < CPL; s8 += 8) {
                size_t ob = obase + s8;
                int cb2 = gcol + s8;
                if (MODE == 0) {
                    *(float4*)(C + ob) = *(float4*)&vA[s8];
                    *(float4*)(C + ob + 4) = *(float4*)&vA[s8 + 4];
                } else {  // MODE 4
                    float4 b0a = *(const float4*)(bias0 + cb2);
                    float4 b0b = *(const float4*)(bias0 + cb2 + 4);
                    float b0v[8] = {b0a.x, b0a.y, b0a.z, b0a.w, b0b.x, b0b.y, b0b.z, b0b.w};
                    float rv[8];
#pragma unroll
                    for (int k = 0; k < 8; ++k) rv[k] = fmaxf(vA[s8 + k] + b0v[k], 0.f);
                    *(float4*)(C + ob) = make_float4(rv[0], rv[1], rv[2], rv[3]);
                    *(float4*)(C + ob + 4) = make_float4(rv[4], rv[5], rv[6], rv[7]);
                }
            }
        }
    }
}

// ---------------- initial split: x -> h planes ----------------
__global__ void split0_kernel(const float* __restrict__ x, unsigned short* __restrict__ hh,
                              unsigned short* __restrict__ hl, int ND4) {
    int i = blockIdx.x * 256 + threadIdx.x;
    if (i >= ND4) return;
    float4 v = ((const float4*)x)[i];
    float vv[4] = {v.x, v.y, v.z, v.w};
    unsigned short hb[4], lb[4];
#pragma unroll
    for (int k = 0; k < 4; ++k) splitf(vv[k], hb[k], lb[k]);
    unsigned long long uh = (unsigned long long)hb[0] | ((unsigned long long)hb[1] << 16) |
                            ((unsigned long long)hb[2] << 32) | ((unsigned long long)hb[3] << 48);
    unsigned long long ul = (unsigned long long)lb[0] | ((unsigned long long)lb[1] << 16) |
                            ((unsigned long long)lb[2] << 32) | ((unsigned long long)lb[3] << 48);
    ((unsigned long long*)hh)[i] = uh;
    ((unsigned long long*)hl)[i] = ul;
}

// ---------------- CSR build ----------------
__global__ void count_kernel(const int* __restrict__ ei, int* __restrict__ cnt, int E) {
    int e = blockIdx.x * 256 + threadIdx.x;
    if (e < E) atomicAdd(&cnt[ei[E + e]], 1);
}

__global__ void scan1_kernel(const int* __restrict__ cnt, int* __restrict__ exc,
                             int* __restrict__ partial, int N) {
    __shared__ int sd[1024];
    int tid = threadIdx.x;
    int base = blockIdx.x * 4096;
    int v[4], s = 0;
#pragma unroll
    for (int i = 0; i < 4; ++i) {
        int idx = base + tid * 4 + i;
        v[i] = (idx < N) ? cnt[idx] : 0;
        s += v[i];
    }
    sd[tid] = s;
    __syncthreads();
    for (int off = 1; off < 1024; off <<= 1) {
        int add = (tid >= off) ? sd[tid - off] : 0;
        __syncthreads();
        sd[tid] += add;
        __syncthreads();
    }
    int ex = sd[tid] - s;
#pragma unroll
    for (int i = 0; i < 4; ++i) {
        int idx = base + tid * 4 + i;
        if (idx < N) exc[idx] = ex;
        ex += v[i];
    }
    if (tid == 1023) partial[blockIdx.x] = sd[1023];
}

__global__ void scan2_kernel(int* __restrict__ partial, int nb) {
    __shared__ int sd[64];
    int tid = threadIdx.x;
    int v = (tid < nb) ? partial[tid] : 0;
    sd[tid] = v;
    __syncthreads();
    for (int off = 1; off < 64; off <<= 1) {
        int add = (tid >= off) ? sd[tid - off] : 0;
        __syncthreads();
        sd[tid] += add;
        __syncthreads();
    }
    if (tid < nb) partial[tid] = sd[tid] - v;
}

__global__ void scan3_kernel(int* __restrict__ row_ptr, const int* __restrict__ partial,
                             int* __restrict__ cursor, int N, int E) {
    int i = blockIdx.x * 256 + threadIdx.x;
    if (i < N) {
        int v = row_ptr[i] + partial[i >> 12];
        row_ptr[i] = v;
        cursor[i] = v;
    }
    if (i == 0) row_ptr[N] = E;
}

__global__ void scatter_kernel(const int* __restrict__ ei, const float* __restrict__ ew,
                               int* __restrict__ cursor, int* __restrict__ src_s,
                               float* __restrict__ ew_s, int E) {
    int e = blockIdx.x * 256 + threadIdx.x;
    if (e < E) {
        int d = ei[E + e];
        int pos = atomicAdd(&cursor[d], 1);
        src_s[pos] = ei[e];
        ew_s[pos] = ew[e];
    }
}

// ---------------- aggregation: m = t[n] + sum w_e * t[src_e], split-write ----------------
__global__ void agg_kernel(const float* __restrict__ t,
                           unsigned short* __restrict__ mh, unsigned short* __restrict__ ml,
                           const int* __restrict__ row_ptr, const int* __restrict__ src_s,
                           const float* __restrict__ ew_s, int N) {
    int n = blockIdx.x * 8 + (threadIdx.x >> 5);
    int c4 = threadIdx.x & 31;
    if (n >= N) return;
    const float4* tp = (const float4*)t;
    float4 a = tp[n * 32 + c4];
    float ax = a.x, ay = a.y, az = a.z, aw = a.w;
    int e0 = row_ptr[n], e1 = row_ptr[n + 1];
    int e = e0;
    for (; e + 4 <= e1; e += 4) {
        int s0 = src_s[e], s1 = src_s[e + 1], s2 = src_s[e + 2], s3 = src_s[e + 3];
        float w0 = ew_s[e], w1 = ew_s[e + 1], w2 = ew_s[e + 2], w3 = ew_s[e + 3];
        float4 v0 = tp[s0 * 32 + c4];
        float4 v1 = tp[s1 * 32 + c4];
        float4 v2 = tp[s2 * 32 + c4];
        float4 v3 = tp[s3 * 32 + c4];
        ax += w0 * v0.x + w1 * v1.x + w2 * v2.x + w3 * v3.x;
        ay += w0 * v0.y + w1 * v1.y + w2 * v2.y + w3 * v3.y;
        az += w0 * v0.z + w1 * v1.z + w2 * v2.z + w3 * v3.z;
        aw += w0 * v0.w + w1 * v1.w + w2 * v2.w + w3 * v3.w;
    }
    for (; e < e1; ++e) {
        int s = src_s[e];
        float w = ew_s[e];
        float4 v = tp[s * 32 + c4];
        ax += w * v.x; ay += w * v.y; az += w * v.z; aw += w * v.w;
    }
    float vv[4] = {ax, ay, az, aw};
    unsigned short hb[4], lb[4];
#pragma unroll
    for (int k = 0; k < 4; ++k) splitf(vv[k], hb[k], lb[k]);
    size_t i8 = (size_t)n * 32 + c4;
    unsigned long long uh = (unsigned long long)hb[0] | ((unsigned long long)hb[1] << 16) |
                            ((unsigned long long)hb[2] << 32) | ((unsigned long long)hb[3] << 48);
    unsigned long long ul = (unsigned long long)lb[0] | ((unsigned long long)lb[1] << 16) |
                            ((unsigned long long)lb[2] << 32) | ((unsigned long long)lb[3] << 48);
    ((unsigned long long*)mh)[i8] = uh;
    ((unsigned long long*)ml)[i8] = ul;
}

// ---------------- bias pack (z, r) ----------------
__global__ void biaspack_kernel(const float* bzm, const float* bzs, const float* bz0,
                                const float* brm, const float* brs, const float* br0,
                                float* bz, float* br) {
    int i = threadIdx.x;
    if (i < D) {
        bz[i] = bzm[i] + bzs[i] + bz0[i];
        br[i] = brm[i] + brs[i] + br0[i];
    }
}

// ---------------- head: hA = h * sigmoid(h@Wg + bg), split-write ----------------
__global__ void att_kernel(const unsigned short* __restrict__ hh, const unsigned short* __restrict__ hl,
                           const float* __restrict__ Wg, const float* __restrict__ bg,
                           unsigned short* __restrict__ oh, unsigned short* __restrict__ ol, int N) {
    int w = threadIdx.x >> 6, l = threadIdx.x & 63;
    int n = blockIdx.x * 4 + w;
    if (n >= N) return;
    size_t base = (size_t)n * D;
    float h0 = bf2f(hh[base + l]) + bf2f(hl[base + l]);
    float h1 = bf2f(hh[base + 64 + l]) + bf2f(hl[base + 64 + l]);
    float p = h0 * Wg[l] + h1 * Wg[64 + l];
#pragma unroll
    for (int off = 32; off; off >>= 1) p += __shfl_xor(p, off);
    float att = sigf(p + bg[0]);
    unsigned short hb, lb;
    splitf(h0 * att, hb, lb);
    oh[base + l] = hb; ol[base + l] = lb;
    splitf(h1 * att, hb, lb);
    oh[base + 64 + l] = hb; ol[base + 64 + l] = lb;
}

__global__ void bounds_kernel(const int* __restrict__ batch, int* __restrict__ gstart,
                              int* __restrict__ gend, int N) {
    int i = blockIdx.x * 256 + threadIdx.x;
    if (i >= N) return;
    int b = batch[i];
    if (i == 0 || batch[i - 1] != b) gstart[b] = i;
    if (i == N - 1 || batch[i + 1] != b) gend[b] = i + 1;
}

__global__ void pool2_kernel(const float* __restrict__ ha, const int* __restrict__ gstart,
                             const int* __restrict__ gend, float* __restrict__ pmax,
                             float* __restrict__ psum) {
    int g = blockIdx.x;
    int slice = blockIdx.y;
    int c = threadIdx.x;
    int s = gstart[g], e = gend[g];
    float vmax = 0.f, vsum = 0.f;
    for (int n = s + slice; n < e; n += PSPLIT) {
        float v = ha[(size_t)n * D + c];
        vmax = fmaxf(vmax, v);
        vsum += v;
    }
    atomicMax((int*)&pmax[g * D + c], __float_as_int(vmax));   // ha >= 0
    atomicAdd(&psum[g * D + c], vsum);
}

__global__ void mlp_kernel(const float* __restrict__ pmax, const float* __restrict__ psum,
                           const int* __restrict__ gstart, const int* __restrict__ gend,
                           const float* __restrict__ W1, const float* __restrict__ b1,
                           const float* __restrict__ W2, const float* __restrict__ b2,
                           float* __restrict__ out) {
    __shared__ float hid[128];
    __shared__ float pg[256];
    int g = blockIdx.x, tid = threadIdx.x;
    int cnt = max(gend[g] - gstart[g], 1);
    if (tid < 128) pg[tid] = pmax[g * D + tid];
    else pg[tid] = psum[g * D + (tid - 128)] / (float)cnt;
    __syncthreads();
    if (tid < 128) {
        float acc = b1[tid];
        for (int k = 0; k < 256; k++) acc += pg[k] * W1[k * 128 + tid];
        hid[tid] = fmaxf(acc, 0.f);
    }
    __syncthreads();
    if (tid < 16) {
        float acc = b2[tid];
        for (int k = 0; k < 128; k++) acc += hid[k] * W2[k * 16 + tid];
        out[g * 16 + tid] = acc;
    }
}

// ---------------- host ----------------
extern "C" void kernel_launch(void* const* d_in, const int* in_sizes, int n_in,
                              void* d_out, int out_size, void* d_ws, size_t ws_size,
                              hipStream_t stream) {
    const float* x       = (const float*)d_in[0];
    const int*   ei      = (const int*)d_in[1];
    const int*   batch   = (const int*)d_in[2];
    const float* ew      = (const float*)d_in[3];
    const float* Wa      = (const float*)d_in[4];
    const float* Wzm     = (const float*)d_in[5];
    const float* bzm     = (const float*)d_in[6];
    const float* Wzs     = (const float*)d_in[7];
    const float* bzs     = (const float*)d_in[8];
    const float* Wrm     = (const float*)d_in[9];
    const float* brm     = (const float*)d_in[10];
    const float* Wrs     = (const float*)d_in[11];
    const float* brs     = (const float*)d_in[12];
    const float* Whm     = (const float*)d_in[13];
    const float* bhm     = (const float*)d_in[14];
    const float* Whs     = (const float*)d_in[15];
    const float* bhs     = (const float*)d_in[16];
    const float* Whg     = (const float*)d_in[17];
    const float* bhg     = (const float*)d_in[18];
    const float* Whl     = (const float*)d_in[19];
    const float* bhl     = (const float*)d_in[20];
    const float* bias_z  = (const float*)d_in[21];
    const float* bias_r  = (const float*)d_in[22];
    const float* bias_h  = (const float*)d_in[23];
    const float* Wag     = (const float*)d_in[24];
    const float* bag     = (const float*)d_in[25];
    const float* Wae     = (const float*)d_in[26];
    const float* bae     = (const float*)d_in[27];
    const float* Wm1     = (const float*)d_in[28];
    const float* bm1     = (const float*)d_in[29];
    const float* Wm2     = (const float*)d_in[30];
    const float* bm2     = (const float*)d_in[31];
    float* out = (float*)d_out;

    const int N = in_sizes[0] / D;
    const int E = in_sizes[1] / 2;
    const size_t ND = (size_t)N * D;

    // workspace layout
    char* p = (char*)d_ws;
    unsigned short* h_hi = (unsigned short*)p;   p += ND * 4;
    unsigned short* h_lo = h_hi + ND;
    float* tz = (float*)p;                       p += ND * 4;   // t, then z; att planes at head
    unsigned short* m_hi = (unsigned short*)p;   p += ND * 4;
    unsigned short* m_lo = m_hi + ND;
    unsigned short* rh_hi = (unsigned short*)p;  p += ND * 4;
    unsigned short* rh_lo = rh_hi + ND;
    int* cnt      = (int*)p;                     p += (size_t)N * 4;
    int* row_ptr  = (int*)p;                     p += (size_t)(N + 2) * 4 + 8;
    int* cursor   = (int*)p;                     p += (size_t)N * 4;
    int* partial  = (int*)p;                     p += 64 * 4;
    int* src_s    = (int*)p;                     p += (size_t)E * 4;
    float* ew_s   = (float*)p;                   p += (size_t)E * 4;
    float* bz     = (float*)p;                   p += D * 4;
    float* br     = (float*)p;                   p += D * 4;
    float* cg     = (float*)p;                   p += D * 4;
    float* cl     = (float*)p;                   p += D * 4;
    int* gstart   = (int*)p;                     p += NGRAPHS * 4;
    int* gend     = (int*)p;                     p += NGRAPHS * 4;
    float* pmax   = (float*)p;                   p += NGRAPHS * D * 4;
    float* psum   = (float*)p;                   p += NGRAPHS * D * 4;
    float* Wmg    = (float*)p;                   p += 16384 * 4;
    float* Wsg    = (float*)p;                   p += 16384 * 4;
    float* Wml    = (float*)p;                   p += 16384 * 4;
    float* Wsl    = (float*)p;                   p += 16384 * 4;
    unsigned short* wfrag = (unsigned short*)p;  p += 10 * 32768 * 2;

    // slots 0..7: dual matrices (32x32 frag order): Zm, Rm, Zs, Rs, Mg, Ml, Sg, Sl
    // slots 8..9: single matrices (16x16 frag order): Wa, Ae
    const unsigned short* wfZm = wfrag + 0 * 32768;
    const unsigned short* wfRm = wfrag + 1 * 32768;
    const unsigned short* wfZs = wfrag + 2 * 32768;
    const unsigned short* wfRs = wfrag + 3 * 32768;
    const unsigned short* wfMg = wfrag + 4 * 32768;
    const unsigned short* wfMl = wfrag + 5 * 32768;
    const unsigned short* wfSg = wfrag + 6 * 32768;
    const unsigned short* wfSl = wfrag + 7 * 32768;
    const unsigned short* wfWa = wfrag + 8 * 32768;
    const unsigned short* wfAe = wfrag + 9 * 32768;

    // views for head stage
    unsigned short* at_hi = (unsigned short*)tz;
    unsigned short* at_lo = at_hi + ND;
    float* embf = (float*)rh_hi;

    const int rowTiles2 = (N + 127) / 128;   // 128-row blocks
    const int gS = rowTiles2 * 2;   // single modes: NJ=4, RT=2, GY=2
    const int gD = rowTiles2 * 4;   // dual 32x32:   4 col groups of 32

    // h planes = split(x)
    split0_kernel<<<(int)((ND / 4 + 255) / 256), 256, 0, stream>>>(x, h_hi, h_lo, (int)(ND / 4));

    // composite weights, then frag prep
    dim3 cgd(2, 129);
    compose_kernel<<<cgd, 256, 0, stream>>>(Whm, Whs, Whg, Whl, bhm, bhs, bias_h, bhg, bhl,
                                            Wmg, Wsg, Wml, Wsl, cg, cl);
    wprepD_kernel<<<8, 256, 0, stream>>>(Wzm, Wrm, Wzs, Wrs, Wmg, Wml, Wsg, Wsl, wfrag);
    wprepS_kernel<<<2, 256, 0, stream>>>(Wa, Wae, wfrag + 8 * 32768);

    // CSR build
    hipMemsetAsync(cnt, 0, (size_t)N * 4, stream);
    count_kernel<<<(E + 255) / 256, 256, 0, stream>>>(ei, cnt, E);
    int nb = (N + 4095) / 4096;
    scan1_kernel<<<nb, 1024, 0, stream>>>(cnt, row_ptr, partial, N);
    scan2_kernel<<<1, 64, 0, stream>>>(partial, nb);
    scan3_kernel<<<(N + 255) / 256, 256, 0, stream>>>(row_ptr, partial, cursor, N, E);
    scatter_kernel<<<(E + 255) / 256, 256, 0, stream>>>(ei, ew, cursor, src_s, ew_s, E);

    biaspack_kernel<<<1, 128, 0, stream>>>(bzm, bzs, bias_z, brm, brs, bias_r, bz, br);

    for (int layer = 0; layer < 3; ++layer) {
        // t = h @ Wa  (f32)
        gmm<0, 4, 2><<<gS, 256, 0, stream>>>(h_hi, h_lo, wfWa, tz, N, rowTiles2, nullptr);
        // m = aggregate(t) -> planes
        agg_kernel<<<(N + 7) / 8, 256, 0, stream>>>(tz, m_hi, m_lo, row_ptr, src_s, ew_s, N);
        // ZR (32x32): z (f32 -> tz) + rh (planes)
        gmm32<1><<<gD, 256, 0, stream>>>(m_hi, m_lo, h_hi, h_lo, wfZm, wfRm, wfZs, wfRs,
                                         tz, rh_hi, rh_lo, N, rowTiles2,
                                         bz, br, nullptr, h_hi, h_lo);
        // GH2 (32x32, composed): h = z*((m@Wml + rh@Wsl + cl)*sig(m@Wmg + rh@Wsg + cg)) + (1-z)*h
        gmm32<3><<<gD, 256, 0, stream>>>(m_hi, m_lo, rh_hi, rh_lo, wfMg, wfMl, wfSg, wfSl,
                                         nullptr, h_hi, h_lo, N, rowTiles2,
                                         cg, cl, tz, h_hi, h_lo);
    }

    // head
    att_kernel<<<(N + 3) / 4, 256, 0, stream>>>(h_hi, h_lo, Wag, bag, at_hi, at_lo, N);
    gmm<4, 4, 2><<<gS, 256, 0, stream>>>(at_hi, at_lo, wfAe, embf, N, rowTiles2, bae);

    hipMemsetAsync(gstart, 0, NGRAPHS * 4, stream);
    hipMemsetAsync(gend, 0, NGRAPHS * 4, stream);
    hipMemsetAsync(pmax, 0, NGRAPHS * D * 4, stream);
    hipMemsetAsync(psum, 0, NGRAPHS * D * 4, stream);
    bounds_kernel<<<(N + 255) / 256, 256, 0, stream>>>(batch, gstart, gend, N);
    dim3 pg(NGRAPHS, PSPLIT);
    pool2_kernel<<<pg, 128, 0, stream>>>(embf, gstart, gend, pmax, psum);
    mlp_kernel<<<NGRAPHS, 256, 0, stream>>>(pmax, psum, gstart, gend, Wm1, bm1, Wm2, bm2, out);
}

// Round 19
// 576.584 us; speedup vs baseline: 1.0549x; 1.0549x over previous
//
#include <hip/hip_runtime.h>
#include <hip/hip_bf16.h>

#define D 128
#define NGRAPHS 64
#define PSPLIT 16

typedef short short8 __attribute__((ext_vector_type(8)));
typedef float f32x4 __attribute__((ext_vector_type(4)));

__device__ __forceinline__ float sigf(float x) { return 1.0f / (1.0f + __expf(-x)); }

__device__ __forceinline__ unsigned short f2bf(float x) {
    unsigned u = __float_as_uint(x);
    return (unsigned short)((u + 0x7fffu + ((u >> 16) & 1u)) >> 16);
}
__device__ __forceinline__ float bf2f(unsigned short u) {
    return __uint_as_float(((unsigned)u) << 16);
}
__device__ __forceinline__ void splitf(float x, unsigned short& hb, unsigned short& lb) {
    hb = f2bf(x);
    lb = f2bf(x - bf2f(hb));
}
#define MFMA(a, b, c) __builtin_amdgcn_mfma_f32_16x16x32_bf16((a), (b), (c), 0, 0, 0)

// async global->LDS, 16B per lane; LDS dest wave-uniform base (+lane*16 implicit)
__device__ __forceinline__ void g2lds16(const unsigned short* g, unsigned short* l) {
    __builtin_amdgcn_global_load_lds(
        (const __attribute__((address_space(1))) void*)g,
        (__attribute__((address_space(3))) void*)l, 16, 0, 0);
}

// XCD-aware block swizzle: all GY col-groups of one row-tile share bid%8 (same XCD L2)
__device__ __forceinline__ void swzmap(int bid, int rowTiles, int GY, int& rt, int& cgp) {
    int chunk = GY << 3;
    int nfull = rowTiles >> 3;
    int fullB = nfull * chunk;
    if (bid < fullB) {
        int q = bid / chunk, r = bid - q * chunk;
        rt = (q << 3) + (r & 7);
        cgp = r >> 3;
    } else {
        int tail = rowTiles - (nfull << 3);
        int rem = bid - fullB;
        rt = (nfull << 3) + rem % tail;
        cgp = rem / tail;
    }
}

// ---------------- composite weights: Wm*=Whm@B, Ws*=Whs@B, c*=bci@B+b2 (B in {Whg,Whl}) ----------------
__global__ void compose_kernel(const float* __restrict__ Whm, const float* __restrict__ Whs,
                               const float* __restrict__ Whg, const float* __restrict__ Whl,
                               const float* __restrict__ bhm, const float* __restrict__ bhs,
                               const float* __restrict__ bias_h,
                               const float* __restrict__ bhg, const float* __restrict__ bhl,
                               float* __restrict__ Wmg, float* __restrict__ Wsg,
                               float* __restrict__ Wml, float* __restrict__ Wsl,
                               float* __restrict__ cg, float* __restrict__ cl) {
    const int sel = blockIdx.x;
    const int r = blockIdx.y;
    const float* B = sel ? Whl : Whg;
    if (r < 128) {
        const int half = threadIdx.x >> 7;
        const int c = threadIdx.x & 127;
        const float* A = half ? Whs : Whm;
        float* O = sel ? (half ? Wsl : Wml) : (half ? Wsg : Wmg);
        float acc = 0.f;
        for (int k = 0; k < 128; ++k) acc += A[r * 128 + k] * B[k * 128 + c];
        O[r * 128 + c] = acc;
    } else if (threadIdx.x < 128) {
        const int c = threadIdx.x;
        float acc = sel ? bhl[c] : bhg[c];
        for (int k = 0; k < 128; ++k)
            acc += (bhm[k] + bhs[k] + bias_h[k]) * B[k * 128 + c];
        (sel ? cl : cg)[c] = acc;
    }
}

// ---------------- weight prep: f32 [128][128] -> frag-ordered bf16 hi/lo ----------------
// frag index f = ((j*4 + t)*64 + lane)*8 + s  maps to  W[t*32 + (lane>>4)*8 + s][j*16 + (lane&15)]
__global__ void wprep_kernel(const float* w0, const float* w1, const float* w2,
                             const float* w3, const float* w4, const float* w5,
                             const float* w6, const float* w7, const float* w8,
                             const float* w9, unsigned short* out) {
    const float* ws[10] = {w0, w1, w2, w3, w4, w5, w6, w7, w8, w9};
    const float* W = ws[blockIdx.x];
    unsigned short* oh = out + (size_t)blockIdx.x * 32768;
    unsigned short* ol = oh + 16384;
    for (int f = threadIdx.x; f < 16384; f += 256) {
        int s = f & 7;
        int lane = (f >> 3) & 63;
        int t = (f >> 9) & 3;
        int j = f >> 11;
        int k = t * 32 + ((lane >> 4) << 3) + s;
        int c = (j << 4) + (lane & 15);
        unsigned short hb, lb;
        splitf(W[k * 128 + c], hb, lb);
        oh[f] = hb;
        ol[f] = lb;
    }
}

// ---------------- MFMA GEMM, column-split, W in LDS, RT row-tiles per wave ----------------
// Block = 4 waves x (RT*16) rows = 64*RT rows x (NJ*16) cols. W ds_reads amortized over RT.
// MODE 0: C = A0@W (f32, no bias)                           [t = h@Wa]
// MODE 1: ZR dual: z = sig(m@Wzm + h@Wzs + b0) -> C f32;
//         rh = sig(m@Wrm + h@Wrs + b1) * h -> planes        [aux = h planes]
// MODE 3: GH2 dual (composed): g = sig(m@Wmg + rh@Wsg + b0);
//         ht = (m@Wml + rh@Wsl + b1) * g;
//         h = z*ht + (1-z)*h_old -> planes                  [auxf = z, aux = h planes]
// MODE 4: relu(A0@W + b0) -> C f32
template <int MODE, int NJ, int RT>
__launch_bounds__(256)
__global__ void gmm(const unsigned short* __restrict__ A0h, const unsigned short* __restrict__ A0l,
                    const unsigned short* __restrict__ A1h, const unsigned short* __restrict__ A1l,
                    const unsigned short* __restrict__ WA0, const unsigned short* __restrict__ WB0,
                    const unsigned short* __restrict__ WA1, const unsigned short* __restrict__ WB1,
                    float* __restrict__ C, unsigned short* __restrict__ Ph, unsigned short* __restrict__ Pl,
                    int N, int rowTiles,
                    const float* __restrict__ bias0, const float* __restrict__ bias1,
                    const float* __restrict__ auxf,
                    const unsigned short* __restrict__ auxh, const unsigned short* __restrict__ auxl) {
    constexpr bool DUAL = (MODE == 1 || MODE == 3);
    constexpr int NP = DUAL ? 2 : 1;
    constexpr int NM = DUAL ? 4 : 1;           // staged matrices
    constexpr int COLS = NJ * 16;
    constexpr int STRIDE = COLS + 4;
    constexpr int CPL = COLS / 4;
    constexpr int GY = 8 / NJ;
    constexpr int MATSH = NJ * 4096;           // shorts per staged matrix slice (hi+lo)
    constexpr int CPM = NJ * 8;                // 1KB chunks per matrix
    constexpr int NCHUNK = NM * CPM;

    __shared__ unsigned short ldsW[NM * MATSH];
    __shared__ float sm[4 * 16 * STRIDE];

    int rtile, by;
    swzmap(blockIdx.x, rowTiles, GY, rtile, by);

    const int tid = threadIdx.x;
    const int wave = tid >> 6;
    const int lane = tid & 63;
    const int r0 = rtile * (64 * RT) + wave * (16 * RT);

    // ---- stage W slices into LDS ----
#pragma unroll
    for (int i = 0; i < NCHUNK / 4; ++i) {
        int c = i * 4 + wave;
        int mat = c / CPM;
        int rem = c - mat * CPM;
        int part = rem / (NJ * 4);             // 0 = hi, 1 = lo
        int sub = rem - part * (NJ * 4);
        const unsigned short* Wsrc = (mat == 0) ? WA0 : (mat == 1) ? WB0 : (mat == 2) ? WA1 : WB1;
        const unsigned short* gsrc = Wsrc + part * 16384 + by * (NJ * 2048) + sub * 512 + lane * 8;
        unsigned short* ldst = &ldsW[mat * MATSH + part * (NJ * 2048) + sub * 512];
        g2lds16(gsrc, ldst);
    }
    __syncthreads();

    f32x4 accA[RT][NJ];
    f32x4 accB[RT][NJ];
#pragma unroll
    for (int rt = 0; rt < RT; ++rt)
#pragma unroll
        for (int j = 0; j < NJ; ++j) {
            accA[rt][j] = (f32x4){0.f, 0.f, 0.f, 0.f};
            accB[rt][j] = (f32x4){0.f, 0.f, 0.f, 0.f};
        }

    int arow[RT];
#pragma unroll
    for (int rt = 0; rt < RT; ++rt) {
        int r = r0 + rt * 16 + (lane & 15);
        arow[rt] = (r < N) ? r : (N - 1);   // clamped rows never stored
    }
    const int kofs = (lane >> 4) << 3;

    // ---- main loop: A global loads + LDS W reads + MFMA ----
#pragma unroll
    for (int p = 0; p < NP; ++p) {
        const unsigned short* __restrict__ Ah = p ? A1h : A0h;
        const unsigned short* __restrict__ Al = p ? A1l : A0l;
        const int matA = DUAL ? (p * 2) : 0;
        const int matB = p * 2 + 1;
#pragma unroll
        for (int t = 0; t < 4; ++t) {
            short8 ah[RT], al[RT];
#pragma unroll
            for (int rt = 0; rt < RT; ++rt) {
                size_t ab = (size_t)arow[rt] * D + t * 32 + kofs;
                ah[rt] = *(const short8*)(Ah + ab);
                al[rt] = *(const short8*)(Al + ab);
            }
#pragma unroll
            for (int jl = 0; jl < NJ; ++jl) {
                int fo = (((jl << 2) + t) << 6) * 8 + lane * 8;
                const unsigned short* whp = &ldsW[matA * MATSH + fo];
                short8 wh = *(const short8*)whp;
                short8 wl = *(const short8*)(whp + NJ * 2048);
#pragma unroll
                for (int rt = 0; rt < RT; ++rt) {
                    accA[rt][jl] = MFMA(ah[rt], wh, accA[rt][jl]);
                    accA[rt][jl] = MFMA(al[rt], wh, accA[rt][jl]);
                    accA[rt][jl] = MFMA(ah[rt], wl, accA[rt][jl]);
                }
                if (DUAL) {
                    const unsigned short* vhp = &ldsW[matB * MATSH + fo];
                    short8 vh = *(const short8*)vhp;
                    short8 vl = *(const short8*)(vhp + NJ * 2048);
#pragma unroll
                    for (int rt = 0; rt < RT; ++rt) {
                        accB[rt][jl] = MFMA(ah[rt], vh, accB[rt][jl]);
                        accB[rt][jl] = MFMA(al[rt], vh, accB[rt][jl]);
                        accB[rt][jl] = MFMA(ah[rt], vl, accB[rt][jl]);
                    }
                }
            }
        }
    }

    // ---- epilogue via wave-local LDS transpose (no barrier: wave-lockstep) ----
    float* mw = sm + wave * (16 * STRIDE);
    const int col0 = lane & 15;
    const int rb = (lane >> 4) << 2;
    const int lr = lane >> 2;
    const int cs = (lane & 3) * CPL;
    const int gcol = by * COLS + cs;

#pragma unroll
    for (int rt = 0; rt < RT; ++rt) {
        const int grow = r0 + rt * 16 + lr;
        const bool live = (grow < N);
        const size_t obase = (size_t)grow * D + gcol;

        float vA[CPL], vB[CPL];
#pragma unroll
        for (int jl = 0; jl < NJ; ++jl)
#pragma unroll
            for (int reg = 0; reg < 4; ++reg)
                mw[(rb + reg) * STRIDE + jl * 16 + col0] = accA[rt][jl][reg];
#pragma unroll
        for (int k = 0; k < CPL; k += 4)
            *(f32x4*)&vA[k] = *(const f32x4*)&mw[lr * STRIDE + cs + k];
        if (DUAL) {
#pragma unroll
            for (int jl = 0; jl < NJ; ++jl)
#pragma unroll
                for (int reg = 0; reg < 4; ++reg)
                    mw[(rb + reg) * STRIDE + jl * 16 + col0] = accB[rt][jl][reg];
#pragma unroll
            for (int k = 0; k < CPL; k += 4)
                *(f32x4*)&vB[k] = *(const f32x4*)&mw[lr * STRIDE + cs + k];
        }

        if (live) {
#pragma unroll
            for (int s8 = 0; s8 < CPL; s8 += 8) {
                size_t ob = obase + s8;
                int cb = gcol + s8;
                if (MODE == 0) {
                    *(float4*)(C + ob) = *(float4*)&vA[s8];
                    *(float4*)(C + ob + 4) = *(float4*)&vA[s8 + 4];
                } else if (MODE == 1) {
                    float4 b0a = *(const float4*)(bias0 + cb);
                    float4 b0b = *(const float4*)(bias0 + cb + 4);
                    float4 b1a = *(const float4*)(bias1 + cb);
                    float4 b1b = *(const float4*)(bias1 + cb + 4);
                    float b0v[8] = {b0a.x, b0a.y, b0a.z, b0a.w, b0b.x, b0b.y, b0b.z, b0b.w};
                    float b1v[8] = {b1a.x, b1a.y, b1a.z, b1a.w, b1b.x, b1b.y, b1b.z, b1b.w};
                    short8 hh8 = *(const short8*)(auxh + ob);
                    short8 ll8 = *(const short8*)(auxl + ob);
                    float zv[8];
                    short8 sh, sl;
#pragma unroll
                    for (int k = 0; k < 8; ++k) {
                        zv[k] = sigf(vA[s8 + k] + b0v[k]);
                        float rr = sigf(vB[s8 + k] + b1v[k]);
                        float hv = bf2f((unsigned short)hh8[k]) + bf2f((unsigned short)ll8[k]);
                        unsigned short hb, lb;
                        splitf(rr * hv, hb, lb);
                        sh[k] = (short)hb; sl[k] = (short)lb;
                    }
                    *(float4*)(C + ob) = make_float4(zv[0], zv[1], zv[2], zv[3]);
                    *(float4*)(C + ob + 4) = make_float4(zv[4], zv[5], zv[6], zv[7]);
                    *(short8*)(Ph + ob) = sh;
                    *(short8*)(Pl + ob) = sl;
                } else if (MODE == 3) {
                    float4 b0a = *(const float4*)(bias0 + cb);
                    float4 b0b = *(const float4*)(bias0 + cb + 4);
                    float4 b1a = *(const float4*)(bias1 + cb);
                    float4 b1b = *(const float4*)(bias1 + cb + 4);
                    float b0v[8] = {b0a.x, b0a.y, b0a.z, b0a.w, b0b.x, b0b.y, b0b.z, b0b.w};
                    float b1v[8] = {b1a.x, b1a.y, b1a.z, b1a.w, b1b.x, b1b.y, b1b.z, b1b.w};
                    float4 za = *(const float4*)(auxf + ob);
                    float4 zb = *(const float4*)(auxf + ob + 4);
                    float zzv[8] = {za.x, za.y, za.z, za.w, zb.x, zb.y, zb.z, zb.w};
                    short8 hh8 = *(const short8*)(auxh + ob);
                    short8 ll8 = *(const short8*)(auxl + ob);
                    short8 sh, sl;
#pragma unroll
                    for (int k = 0; k < 8; ++k) {
                        float g = sigf(vA[s8 + k] + b0v[k]);
                        float ht = (vB[s8 + k] + b1v[k]) * g;
                        float hv = bf2f((unsigned short)hh8[k]) + bf2f((unsigned short)ll8[k]);
                        float v = zzv[k] * ht + (1.f - zzv[k]) * hv;
                        unsigned short hb, lb;
                        splitf(v, hb, lb);
                        sh[k] = (short)hb; sl[k] = (short)lb;
                    }
                    *(short8*)(Ph + ob) = sh;
                    *(short8*)(Pl + ob) = sl;
                } else {  // MODE 4
                    float4 b0a = *(const float4*)(bias0 + cb);
                    float4 b0b = *(const float4*)(bias0 + cb + 4);
                    float b0v[8] = {b0a.x, b0a.y, b0a.z, b0a.w, b0b.x, b0b.y, b0b.z, b0b.w};
                    float rv[8];
#pragma unroll
                    for (int k = 0; k < 8; ++k) rv[k] = fmaxf(vA[s8 + k] + b0v[k], 0.f);
                    *(float4*)(C + ob) = make_float4(rv[0], rv[1], rv[2], rv[3]);
                    *(float4*)(C + ob + 4) = make_float4(rv[4], rv[5], rv[6], rv[7]);
                }
            }
        }
    }
}

// ---------------- initial split: x -> h planes ----------------
__global__ void split0_kernel(const float* __restrict__ x, unsigned short* __restrict__ hh,
                              unsigned short* __restrict__ hl, int ND4) {
    int i = blockIdx.x * 256 + threadIdx.x;
    if (i >= ND4) return;
    float4 v = ((const float4*)x)[i];
    float vv[4] = {v.x, v.y, v.z, v.w};
    unsigned short hb[4], lb[4];
#pragma unroll
    for (int k = 0; k < 4; ++k) splitf(vv[k], hb[k], lb[k]);
    unsigned long long uh = (unsigned long long)hb[0] | ((unsigned long long)hb[1] << 16) |
                            ((unsigned long long)hb[2] << 32) | ((unsigned long long)hb[3] << 48);
    unsigned long long ul = (unsigned long long)lb[0] | ((unsigned long long)lb[1] << 16) |
                            ((unsigned long long)lb[2] << 32) | ((unsigned long long)lb[3] << 48);
    ((unsigned long long*)hh)[i] = uh;
    ((unsigned long long*)hl)[i] = ul;
}

// ---------------- CSR build ----------------
__global__ void count_kernel(const int* __restrict__ ei, int* __restrict__ cnt, int E) {
    int e = blockIdx.x * 256 + threadIdx.x;
    if (e < E) atomicAdd(&cnt[ei[E + e]], 1);
}

__global__ void scan1_kernel(const int* __restrict__ cnt, int* __restrict__ exc,
                             int* __restrict__ partial, int N) {
    __shared__ int sd[1024];
    int tid = threadIdx.x;
    int base = blockIdx.x * 4096;
    int v[4], s = 0;
#pragma unroll
    for (int i = 0; i < 4; ++i) {
        int idx = base + tid * 4 + i;
        v[i] = (idx < N) ? cnt[idx] : 0;
        s += v[i];
    }
    sd[tid] = s;
    __syncthreads();
    for (int off = 1; off < 1024; off <<= 1) {
        int add = (tid >= off) ? sd[tid - off] : 0;
        __syncthreads();
        sd[tid] += add;
        __syncthreads();
    }
    int ex = sd[tid] - s;
#pragma unroll
    for (int i = 0; i < 4; ++i) {
        int idx = base + tid * 4 + i;
        if (idx < N) exc[idx] = ex;
        ex += v[i];
    }
    if (tid == 1023) partial[blockIdx.x] = sd[1023];
}

__global__ void scan2_kernel(int* __restrict__ partial, int nb) {
    __shared__ int sd[64];
    int tid = threadIdx.x;
    int v = (tid < nb) ? partial[tid] : 0;
    sd[tid] = v;
    __syncthreads();
    for (int off = 1; off < 64; off <<= 1) {
        int add = (tid >= off) ? sd[tid - off] : 0;
        __syncthreads();
        sd[tid] += add;
        __syncthreads();
    }
    if (tid < nb) partial[tid] = sd[tid] - v;
}

__global__ void scan3_kernel(int* __restrict__ row_ptr, const int* __restrict__ partial,
                             int* __restrict__ cursor, int N, int E) {
    int i = blockIdx.x * 256 + threadIdx.x;
    if (i < N) {
        int v = row_ptr[i] + partial[i >> 12];
        row_ptr[i] = v;
        cursor[i] = v;
    }
    if (i == 0) row_ptr[N] = E;
}

__global__ void scatter_kernel(const int* __restrict__ ei, const float* __restrict__ ew,
                               int* __restrict__ cursor, int* __restrict__ src_s,
                               float* __restrict__ ew_s, int E) {
    int e = blockIdx.x * 256 + threadIdx.x;
    if (e < E) {
        int d = ei[E + e];
        int pos = atomicAdd(&cursor[d], 1);
        src_s[pos] = ei[e];
        ew_s[pos] = ew[e];
    }
}

// ---------------- aggregation: m = t[n] + sum w_e * t[src_e], split-write ----------------
__global__ void agg_kernel(const float* __restrict__ t,
                           unsigned short* __restrict__ mh, unsigned short* __restrict__ ml,
                           const int* __restrict__ row_ptr, const int* __restrict__ src_s,
                           const float* __restrict__ ew_s, int N) {
    int n = blockIdx.x * 8 + (threadIdx.x >> 5);
    int c4 = threadIdx.x & 31;
    if (n >= N) return;
    const float4* tp = (const float4*)t;
    float4 a = tp[n * 32 + c4];
    float ax = a.x, ay = a.y, az = a.z, aw = a.w;
    int e0 = row_ptr[n], e1 = row_ptr[n + 1];
    int e = e0;
    for (; e + 4 <= e1; e += 4) {
        int s0 = src_s[e], s1 = src_s[e + 1], s2 = src_s[e + 2], s3 = src_s[e + 3];
        float w0 = ew_s[e], w1 = ew_s[e + 1], w2 = ew_s[e + 2], w3 = ew_s[e + 3];
        float4 v0 = tp[s0 * 32 + c4];
        float4 v1 = tp[s1 * 32 + c4];
        float4 v2 = tp[s2 * 32 + c4];
        float4 v3 = tp[s3 * 32 + c4];
        ax += w0 * v0.x + w1 * v1.x + w2 * v2.x + w3 * v3.x;
        ay += w0 * v0.y + w1 * v1.y + w2 * v2.y + w3 * v3.y;
        az += w0 * v0.z + w1 * v1.z + w2 * v2.z + w3 * v3.z;
        aw += w0 * v0.w + w1 * v1.w + w2 * v2.w + w3 * v3.w;
    }
    for (; e < e1; ++e) {
        int s = src_s[e];
        float w = ew_s[e];
        float4 v = tp[s * 32 + c4];
        ax += w * v.x; ay += w * v.y; az += w * v.z; aw += w * v.w;
    }
    float vv[4] = {ax, ay, az, aw};
    unsigned short hb[4], lb[4];
#pragma unroll
    for (int k = 0; k < 4; ++k) splitf(vv[k], hb[k], lb[k]);
    size_t i8 = (size_t)n * 32 + c4;
    unsigned long long uh = (unsigned long long)hb[0] | ((unsigned long long)hb[1] << 16) |
                            ((unsigned long long)hb[2] << 32) | ((unsigned long long)hb[3] << 48);
    unsigned long long ul = (unsigned long long)lb[0] | ((unsigned long long)lb[1] << 16) |
                            ((unsigned long long)lb[2] << 32) | ((unsigned long long)lb[3] << 48);
    ((unsigned long long*)mh)[i8] = uh;
    ((unsigned long long*)ml)[i8] = ul;
}

// ---------------- bias pack (z, r) ----------------
__global__ void biaspack_kernel(const float* bzm, const float* bzs, const float* bz0,
                                const float* brm, const float* brs, const float* br0,
                                float* bz, float* br) {
    int i = threadIdx.x;
    if (i < D) {
        bz[i] = bzm[i] + bzs[i] + bz0[i];
        br[i] = brm[i] + brs[i] + br0[i];
    }
}

// ---------------- head: hA = h * sigmoid(h@Wg + bg), split-write ----------------
__global__ void att_kernel(const unsigned short* __restrict__ hh, const unsigned short* __restrict__ hl,
                           const float* __restrict__ Wg, const float* __restrict__ bg,
                           unsigned short* __restrict__ oh, unsigned short* __restrict__ ol, int N) {
    int w = threadIdx.x >> 6, l = threadIdx.x & 63;
    int n = blockIdx.x * 4 + w;
    if (n >= N) return;
    size_t base = (size_t)n * D;
    float h0 = bf2f(hh[base + l]) + bf2f(hl[base + l]);
    float h1 = bf2f(hh[base + 64 + l]) + bf2f(hl[base + 64 + l]);
    float p = h0 * Wg[l] + h1 * Wg[64 + l];
#pragma unroll
    for (int off = 32; off; off >>= 1) p += __shfl_xor(p, off);
    float att = sigf(p + bg[0]);
    unsigned short hb, lb;
    splitf(h0 * att, hb, lb);
    oh[base + l] = hb; ol[base + l] = lb;
    splitf(h1 * att, hb, lb);
    oh[base + 64 + l] = hb; ol[base + 64 + l] = lb;
}

__global__ void bounds_kernel(const int* __restrict__ batch, int* __restrict__ gstart,
                              int* __restrict__ gend, int N) {
    int i = blockIdx.x * 256 + threadIdx.x;
    if (i >= N) return;
    int b = batch[i];
    if (i == 0 || batch[i - 1] != b) gstart[b] = i;
    if (i == N - 1 || batch[i + 1] != b) gend[b] = i + 1;
}

__global__ void pool2_kernel(const float* __restrict__ ha, const int* __restrict__ gstart,
                             const int* __restrict__ gend, float* __restrict__ pmax,
                             float* __restrict__ psum) {
    int g = blockIdx.x;
    int slice = blockIdx.y;
    int c = threadIdx.x;
    int s = gstart[g], e = gend[g];
    float vmax = 0.f, vsum = 0.f;
    for (int n = s + slice; n < e; n += PSPLIT) {
        float v = ha[(size_t)n * D + c];
        vmax = fmaxf(vmax, v);
        vsum += v;
    }
    atomicMax((int*)&pmax[g * D + c], __float_as_int(vmax));   // ha >= 0
    atomicAdd(&psum[g * D + c], vsum);
}

__global__ void mlp_kernel(const float* __restrict__ pmax, const float* __restrict__ psum,
                           const int* __restrict__ gstart, const int* __restrict__ gend,
                           const float* __restrict__ W1, const float* __restrict__ b1,
                           const float* __restrict__ W2, const float* __restrict__ b2,
                           float* __restrict__ out) {
    __shared__ float hid[128];
    __shared__ float pg[256];
    int g = blockIdx.x, tid = threadIdx.x;
    int cnt = max(gend[g] - gstart[g], 1);
    if (tid < 128) pg[tid] = pmax[g * D + tid];
    else pg[tid] = psum[g * D + (tid - 128)] / (float)cnt;
    __syncthreads();
    if (tid < 128) {
        float acc = b1[tid];
        for (int k = 0; k < 256; k++) acc += pg[k] * W1[k * 128 + tid];
        hid[tid] = fmaxf(acc, 0.f);
    }
    __syncthreads();
    if (tid < 16) {
        float acc = b2[tid];
        for (int k = 0; k < 128; k++) acc += hid[k] * W2[k * 16 + tid];
        out[g * 16 + tid] = acc;
    }
}

// ---------------- host ----------------
extern "C" void kernel_launch(void* const* d_in, const int* in_sizes, int n_in,
                              void* d_out, int out_size, void* d_ws, size_t ws_size,
                              hipStream_t stream) {
    const float* x       = (const float*)d_in[0];
    const int*   ei      = (const int*)d_in[1];
    const int*   batch   = (const int*)d_in[2];
    const float* ew      = (const float*)d_in[3];
    const float* Wa      = (const float*)d_in[4];
    const float* Wzm     = (const float*)d_in[5];
    const float* bzm     = (const float*)d_in[6];
    const float* Wzs     = (const float*)d_in[7];
    const float* bzs     = (const float*)d_in[8];
    const float* Wrm     = (const float*)d_in[9];
    const float* brm     = (const float*)d_in[10];
    const float* Wrs     = (const float*)d_in[11];
    const float* brs     = (const float*)d_in[12];
    const float* Whm     = (const float*)d_in[13];
    const float* bhm     = (const float*)d_in[14];
    const float* Whs     = (const float*)d_in[15];
    const float* bhs     = (const float*)d_in[16];
    const float* Whg     = (const float*)d_in[17];
    const float* bhg     = (const float*)d_in[18];
    const float* Whl     = (const float*)d_in[19];
    const float* bhl     = (const float*)d_in[20];
    const float* bias_z  = (const float*)d_in[21];
    const float* bias_r  = (const float*)d_in[22];
    const float* bias_h  = (const float*)d_in[23];
    const float* Wag     = (const float*)d_in[24];
    const float* bag     = (const float*)d_in[25];
    const float* Wae     = (const float*)d_in[26];
    const float* bae     = (const float*)d_in[27];
    const float* Wm1     = (const float*)d_in[28];
    const float* bm1     = (const float*)d_in[29];
    const float* Wm2     = (const float*)d_in[30];
    const float* bm2     = (const float*)d_in[31];
    float* out = (float*)d_out;

    const int N = in_sizes[0] / D;
    const int E = in_sizes[1] / 2;
    const size_t ND = (size_t)N * D;

    // workspace layout
    char* p = (char*)d_ws;
    unsigned short* h_hi = (unsigned short*)p;   p += ND * 4;
    unsigned short* h_lo = h_hi + ND;
    float* tz = (float*)p;                       p += ND * 4;   // t, then z; att planes at head
    unsigned short* m_hi = (unsigned short*)p;   p += ND * 4;
    unsigned short* m_lo = m_hi + ND;
    unsigned short* rh_hi = (unsigned short*)p;  p += ND * 4;
    unsigned short* rh_lo = rh_hi + ND;
    int* cnt      = (int*)p;                     p += (size_t)N * 4;
    int* row_ptr  = (int*)p;                     p += (size_t)(N + 2) * 4 + 8;
    int* cursor   = (int*)p;                     p += (size_t)N * 4;
    int* partial  = (int*)p;                     p += 64 * 4;
    int* src_s    = (int*)p;                     p += (size_t)E * 4;
    float* ew_s   = (float*)p;                   p += (size_t)E * 4;
    float* bz     = (float*)p;                   p += D * 4;
    float* br     = (float*)p;                   p += D * 4;
    float* cg     = (float*)p;                   p += D * 4;
    float* cl     = (float*)p;                   p += D * 4;
    int* gstart   = (int*)p;                     p += NGRAPHS * 4;
    int* gend     = (int*)p;                     p += NGRAPHS * 4;
    float* pmax   = (float*)p;                   p += NGRAPHS * D * 4;
    float* psum   = (float*)p;                   p += NGRAPHS * D * 4;
    float* Wmg    = (float*)p;                   p += 16384 * 4;
    float* Wsg    = (float*)p;                   p += 16384 * 4;
    float* Wml    = (float*)p;                   p += 16384 * 4;
    float* Wsl    = (float*)p;                   p += 16384 * 4;
    unsigned short* wfrag = (unsigned short*)p;  p += 10 * 32768 * 2;

    const unsigned short* wfWa = wfrag + 0 * 32768;
    const unsigned short* wfZm = wfrag + 1 * 32768;
    const unsigned short* wfZs = wfrag + 2 * 32768;
    const unsigned short* wfRm = wfrag + 3 * 32768;
    const unsigned short* wfRs = wfrag + 4 * 32768;
    const unsigned short* wfMg = wfrag + 5 * 32768;
    const unsigned short* wfSg = wfrag + 6 * 32768;
    const unsigned short* wfMl = wfrag + 7 * 32768;
    const unsigned short* wfSl = wfrag + 8 * 32768;
    const unsigned short* wfAe = wfrag + 9 * 32768;

    // views for head stage
    unsigned short* at_hi = (unsigned short*)tz;
    unsigned short* at_lo = at_hi + ND;
    float* embf = (float*)rh_hi;

    const int rowTiles2 = (N + 127) / 128;   // RT=2: 128 rows per block
    const int gS = rowTiles2 * 2;   // single modes: NJ=4, RT=2, GY=2
    const int gD = rowTiles2 * 4;   // dual modes:   NJ=2, RT=2, GY=4

    // h planes = split(x)
    split0_kernel<<<(int)((ND / 4 + 255) / 256), 256, 0, stream>>>(x, h_hi, h_lo, (int)(ND / 4));

    // composite weights, then frag prep
    dim3 cgd(2, 129);
    compose_kernel<<<cgd, 256, 0, stream>>>(Whm, Whs, Whg, Whl, bhm, bhs, bias_h, bhg, bhl,
                                            Wmg, Wsg, Wml, Wsl, cg, cl);
    wprep_kernel<<<10, 256, 0, stream>>>(Wa, Wzm, Wzs, Wrm, Wrs, Wmg, Wsg, Wml, Wsl, Wae, wfrag);

    // CSR build
    hipMemsetAsync(cnt, 0, (size_t)N * 4, stream);
    count_kernel<<<(E + 255) / 256, 256, 0, stream>>>(ei, cnt, E);
    int nb = (N + 4095) / 4096;
    scan1_kernel<<<nb, 1024, 0, stream>>>(cnt, row_ptr, partial, N);
    scan2_kernel<<<1, 64, 0, stream>>>(partial, nb);
    scan3_kernel<<<(N + 255) / 256, 256, 0, stream>>>(row_ptr, partial, cursor, N, E);
    scatter_kernel<<<(E + 255) / 256, 256, 0, stream>>>(ei, ew, cursor, src_s, ew_s, E);

    biaspack_kernel<<<1, 128, 0, stream>>>(bzm, bzs, bias_z, brm, brs, bias_r, bz, br);

    for (int layer = 0; layer < 3; ++layer) {
        // t = h @ Wa  (f32)
        gmm<0, 4, 2><<<gS, 256, 0, stream>>>(h_hi, h_lo, nullptr, nullptr, wfWa, nullptr, nullptr, nullptr,
                                             tz, nullptr, nullptr, N, rowTiles2,
                                             nullptr, nullptr, nullptr, nullptr, nullptr);
        // m = aggregate(t) -> planes
        agg_kernel<<<(N + 7) / 8, 256, 0, stream>>>(tz, m_hi, m_lo, row_ptr, src_s, ew_s, N);
        // z (f32 -> tz) and rh (planes) fused
        gmm<1, 2, 2><<<gD, 256, 0, stream>>>(m_hi, m_lo, h_hi, h_lo, wfZm, wfRm, wfZs, wfRs,
                                             tz, rh_hi, rh_lo, N, rowTiles2,
                                             bz, br, nullptr, h_hi, h_lo);
        // GH2 (composed): g = sig(m@Wmg + rh@Wsg + cg); ht = (m@Wml + rh@Wsl + cl)*g;
        // h = z*ht + (1-z)*h  (elementwise-aligned in-place over h planes)
        gmm<3, 2, 2><<<gD, 256, 0, stream>>>(m_hi, m_lo, rh_hi, rh_lo, wfMg, wfMl, wfSg, wfSl,
                                             nullptr, h_hi, h_lo, N, rowTiles2,
                                             cg, cl, tz, h_hi, h_lo);
    }

    // head
    att_kernel<<<(N + 3) / 4, 256, 0, stream>>>(h_hi, h_lo, Wag, bag, at_hi, at_lo, N);
    gmm<4, 4, 2><<<gS, 256, 0, stream>>>(at_hi, at_lo, nullptr, nullptr, wfAe, nullptr, nullptr, nullptr,
                                         embf, nullptr, nullptr, N, rowTiles2,
                                         bae, nullptr, nullptr, nullptr, nullptr);

    hipMemsetAsync(gstart, 0, NGRAPHS * 4, stream);
    hipMemsetAsync(gend, 0, NGRAPHS * 4, stream);
    hipMemsetAsync(pmax, 0, NGRAPHS * D * 4, stream);
    hipMemsetAsync(psum, 0, NGRAPHS * D * 4, stream);
    bounds_kernel<<<(N + 255) / 256, 256, 0, stream>>>(batch, gstart, gend, N);
    dim3 pg(NGRAPHS, PSPLIT);
    pool2_kernel<<<pg, 128, 0, stream>>>(embf, gstart, gend, pmax, psum);
    mlp_kernel<<<NGRAPHS, 256, 0, stream>>>(pmax, psum, gstart, gend, Wm1, bm1, Wm2, bm2, out);
}